// Round 1
// baseline (178.530 us; speedup 1.0000x reference)
//
#include <hip/hip_runtime.h>
#include <hip/hip_bf16.h>
#include <cstdint>

#define B_SZ  4096
#define N_POS 512
#define N_CLS 512
#define PHI   128
#define H1D   512
#define H2D   256

__device__ __forceinline__ unsigned int bf16rne(float f) {
  unsigned int x = __float_as_uint(f);
  return (x + 0x7fffu + ((x >> 16) & 1u)) >> 16;
}
__device__ __forceinline__ float bflo(unsigned int p) { return __uint_as_float(p << 16); }
__device__ __forceinline__ float bfhi(unsigned int p) { return __uint_as_float(p & 0xffff0000u); }

// ---------------------------------------------------------------------------
// Kernel A: u[b][phi] = sum_n W_phi[x[b][n]][phi] + 512*b_phi[phi]
// grid (B/32, 2 phi-halves), 256 threads. Stages half the table (512 cls x 64
// phi) as bf16 pairs in 64 KB LDS; each thread owns (row-slot, 8-phi octet).
// ---------------------------------------------------------------------------
__global__ __launch_bounds__(256) void gather_u(
    const int* __restrict__ x, const float* __restrict__ W_phi,
    const float* __restrict__ b_phi, float* __restrict__ u) {
  __shared__ unsigned int tbl[N_CLS * 32];  // 512 * 32 u32 = 64 KB (bf16 pairs)
  const int tid  = threadIdx.x;
  const int half = blockIdx.y;

  // stage: 512 cls x 64 floats = 8192 float4, 32 per thread, coalesced
  const float4* W4 = (const float4*)W_phi;
  #pragma unroll 4
  for (int it = 0; it < 32; ++it) {
    int f  = it * 256 + tid;      // float4 index within half-table
    int c  = f >> 4;              // class
    int w4 = f & 15;              // float4 within the 64-float half-row
    float4 v = W4[c * 32 + half * 16 + w4];
    tbl[c * 32 + w4 * 2]     = bf16rne(v.x) | (bf16rne(v.y) << 16);
    tbl[c * 32 + w4 * 2 + 1] = bf16rne(v.z) | (bf16rne(v.w) << 16);
  }
  __syncthreads();

  const int rs  = tid >> 3;              // row slot 0..31
  const int oc  = tid & 7;               // phi octet 0..7
  const int row = blockIdx.x * 32 + rs;
  const int* xrow = x + row * N_POS;

  float acc[8];
  #pragma unroll
  for (int e = 0; e < 8; ++e) acc[e] = 0.0f;

  for (int n0 = 0; n0 < N_POS; n0 += 4) {
    int4 xi = *(const int4*)(xrow + n0);
    int cc[4] = {xi.x, xi.y, xi.z, xi.w};
    #pragma unroll
    for (int q = 0; q < 4; ++q) {
      uint4 t = *(const uint4*)(tbl + cc[q] * 32 + oc * 4);  // 8 bf16
      acc[0] += bflo(t.x); acc[1] += bfhi(t.x);
      acc[2] += bflo(t.y); acc[3] += bfhi(t.y);
      acc[4] += bflo(t.z); acc[5] += bfhi(t.z);
      acc[6] += bflo(t.w); acc[7] += bfhi(t.w);
    }
  }

  const int pbase = half * 64 + oc * 8;
  float o[8];
  #pragma unroll
  for (int e = 0; e < 8; ++e)
    o[e] = acc[e] + 512.0f * b_phi[pbase + e];
  float4* up = (float4*)(u + row * PHI + pbase);
  up[0] = make_float4(o[0], o[1], o[2], o[3]);
  up[1] = make_float4(o[4], o[5], o[6], o[7]);
}

// ---------------------------------------------------------------------------
// Tiled fp32 GEMM: C = relu(A @ B + bias). A: MxK, B: KxN, row-major.
// 128x64 tile / block, 256 threads, 8x4 per thread, TK=16.
// Requires M%128==0, N%64==0, K%16==0.
// ---------------------------------------------------------------------------
template<int RELU>
__global__ __launch_bounds__(256) void gemm_f32(
    const float* __restrict__ A, const float* __restrict__ Bm,
    const float* __restrict__ bias, float* __restrict__ C,
    int M, int N, int K) {
  __shared__ float AsT[16][128];  // transposed A chunk
  __shared__ float Bs[16][64];
  const int tid = threadIdx.x;
  const int bm = blockIdx.x * 128;
  const int bn = blockIdx.y * 64;
  const int tm = (tid >> 4) << 3;   // 0..120 step 8
  const int tn = (tid & 15) << 2;   // 0..60  step 4

  float acc[8][4];
  #pragma unroll
  for (int i = 0; i < 8; ++i)
    #pragma unroll
    for (int j = 0; j < 4; ++j) acc[i][j] = 0.0f;

  for (int k0 = 0; k0 < K; k0 += 16) {
    __syncthreads();
    // A chunk: 128 rows x 16 k = 512 float4, 2 per thread (transpose into LDS)
    #pragma unroll
    for (int it = 0; it < 2; ++it) {
      int f  = it * 256 + tid;
      int r  = f >> 2;           // 0..127
      int k4 = (f & 3) << 2;     // 0,4,8,12
      float4 v = *(const float4*)(A + (size_t)(bm + r) * K + k0 + k4);
      AsT[k4 + 0][r] = v.x;
      AsT[k4 + 1][r] = v.y;
      AsT[k4 + 2][r] = v.z;
      AsT[k4 + 3][r] = v.w;
    }
    // B chunk: 16 k x 64 n = 256 float4, 1 per thread
    {
      int kr = tid >> 4;
      int n4 = (tid & 15) << 2;
      *(float4*)&Bs[kr][n4] = *(const float4*)(Bm + (size_t)(k0 + kr) * N + bn + n4);
    }
    __syncthreads();

    #pragma unroll
    for (int kk = 0; kk < 16; ++kk) {
      float4 b4 = *(const float4*)&Bs[kk][tn];
      float4 a0 = *(const float4*)&AsT[kk][tm];
      float4 a1 = *(const float4*)&AsT[kk][tm + 4];
      float av[8] = {a0.x, a0.y, a0.z, a0.w, a1.x, a1.y, a1.z, a1.w};
      float bv[4] = {b4.x, b4.y, b4.z, b4.w};
      #pragma unroll
      for (int i = 0; i < 8; ++i)
        #pragma unroll
        for (int j = 0; j < 4; ++j)
          acc[i][j] += av[i] * bv[j];
    }
  }

  float4 bb = *(const float4*)(bias + bn + tn);
  float bv[4] = {bb.x, bb.y, bb.z, bb.w};
  #pragma unroll
  for (int i = 0; i < 8; ++i) {
    float4 o;
    o.x = acc[i][0] + bv[0];
    o.y = acc[i][1] + bv[1];
    o.z = acc[i][2] + bv[2];
    o.w = acc[i][3] + bv[3];
    if (RELU) {
      o.x = fmaxf(o.x, 0.0f); o.y = fmaxf(o.y, 0.0f);
      o.z = fmaxf(o.z, 0.0f); o.w = fmaxf(o.w, 0.0f);
    }
    *(float4*)(C + (size_t)(bm + tm + i) * N + bn + tn) = o;
  }
}

// ---------------------------------------------------------------------------
// Kernel D: out[b] = dot(h2[b], W3) + b3.  One wave per 16 rows.
// grid 64 blocks x 256 threads (4 waves), 16 rows per wave.
// ---------------------------------------------------------------------------
__global__ __launch_bounds__(256) void matvec_out(
    const float* __restrict__ h2, const float* __restrict__ W3,
    const float* __restrict__ b3, float* __restrict__ out) {
  __shared__ float w[H2D];
  const int tid = threadIdx.x;
  w[tid] = W3[tid];
  __syncthreads();
  const int wave = tid >> 6, lane = tid & 63;
  const float b3v = b3[0];
  const float4 wv = *(const float4*)&w[lane * 4];
  #pragma unroll 4
  for (int r = 0; r < 16; ++r) {
    int row = (blockIdx.x * 4 + wave) * 16 + r;
    float4 v = *(const float4*)(h2 + (size_t)row * H2D + lane * 4);
    float s = v.x * wv.x + v.y * wv.y + v.z * wv.z + v.w * wv.w;
    #pragma unroll
    for (int off = 32; off > 0; off >>= 1) s += __shfl_down(s, off, 64);
    if (lane == 0) out[row] = s + b3v;
  }
}

// ---------------------------------------------------------------------------
extern "C" void kernel_launch(void* const* d_in, const int* in_sizes, int n_in,
                              void* d_out, int out_size, void* d_ws, size_t ws_size,
                              hipStream_t stream) {
  const int*   x     = (const int*)  d_in[0];
  const float* W_phi = (const float*)d_in[1];
  const float* b_phi = (const float*)d_in[2];
  const float* W1    = (const float*)d_in[3];
  const float* b1    = (const float*)d_in[4];
  const float* W2    = (const float*)d_in[5];
  const float* b2    = (const float*)d_in[6];
  const float* W3    = (const float*)d_in[7];
  const float* b3    = (const float*)d_in[8];
  float* out = (float*)d_out;

  char* ws = (char*)d_ws;
  float* u  = (float*)(ws);
  float* h1 = (float*)(ws + (size_t)B_SZ * PHI * 4);
  float* h2 = (float*)(ws + (size_t)B_SZ * PHI * 4 + (size_t)B_SZ * H1D * 4);

  gather_u<<<dim3(B_SZ / 32, 2), 256, 0, stream>>>(x, W_phi, b_phi, u);
  gemm_f32<1><<<dim3(B_SZ / 128, H1D / 64), 256, 0, stream>>>(u, W1, b1, h1, B_SZ, H1D, PHI);
  gemm_f32<1><<<dim3(B_SZ / 128, H2D / 64), 256, 0, stream>>>(h1, W2, b2, h2, B_SZ, H2D, H1D);
  matvec_out<<<B_SZ / 64, 256, 0, stream>>>(h2, W3, b3, out);
}

// Round 2
// 126.741 us; speedup vs baseline: 1.4086x; 1.4086x over previous
//
#include <hip/hip_runtime.h>
#include <hip/hip_bf16.h>
#include <cstdint>

#define B_SZ  4096
#define N_POS 512
#define N_CLS 512
#define PHI   128
#define H1D   512
#define H2D   256

typedef short bf16x8 __attribute__((ext_vector_type(8)));
typedef float f32x4  __attribute__((ext_vector_type(4)));

__device__ __forceinline__ unsigned int bf16rne(float f) {
  unsigned int x = __float_as_uint(f);
  return (x + 0x7fffu + ((x >> 16) & 1u)) >> 16;
}
__device__ __forceinline__ float bflo(unsigned int p) { return __uint_as_float(p << 16); }
__device__ __forceinline__ float bfhi(unsigned int p) { return __uint_as_float(p & 0xffff0000u); }

__device__ __forceinline__ void gload16(const void* g, void* l) {
  __builtin_amdgcn_global_load_lds(
      (const __attribute__((address_space(1))) unsigned int*)g,
      (__attribute__((address_space(3))) unsigned int*)l, 16, 0, 0);
}

// ---------------------------------------------------------------------------
// prep: W1T (512x128 bf16), W2T (256x512 bf16), b1eff = b1 + (512*b_phi)@W1
// grid 770 x 256
// ---------------------------------------------------------------------------
__global__ __launch_bounds__(256) void prep(
    const float* __restrict__ W1, const float* __restrict__ W2,
    const float* __restrict__ b_phi, const float* __restrict__ b1,
    unsigned short* __restrict__ W1T, unsigned short* __restrict__ W2T,
    float* __restrict__ b1eff) {
  const int b = blockIdx.x, tid = threadIdx.x;
  if (b < 256) {                       // W1T[j][p] = W1[p][j]
    int o = b * 256 + tid;
    int j = o >> 7, p = o & 127;
    W1T[o] = (unsigned short)bf16rne(W1[p * 512 + j]);
  } else if (b < 768) {                // W2T[n][k] = W2[k][n]
    int o = (b - 256) * 256 + tid;
    int n = o >> 9, k = o & 511;
    W2T[o] = (unsigned short)bf16rne(W2[k * 256 + n]);
  } else {                             // b1eff
    int j = (b - 768) * 256 + tid;
    float a = 0.0f;
    #pragma unroll 8
    for (int p = 0; p < PHI; ++p) a += b_phi[p] * W1[p * 512 + j];
    b1eff[j] = b1[j] + 512.0f * a;
  }
}

// ---------------------------------------------------------------------------
// gather: s[b][phi] = sum_n W_phi[x[b][n]][phi]  (bias folded into b1eff),
// output bf16. grid (B/32, 2 phi-halves), 256 threads, 64KB LDS bf16 table.
// ---------------------------------------------------------------------------
__global__ __launch_bounds__(256) void gather_u(
    const int* __restrict__ x, const float* __restrict__ W_phi,
    unsigned short* __restrict__ u_bf) {
  __shared__ unsigned int tbl[N_CLS * 32];  // 512 cls x 64 phi as bf16 pairs
  const int tid  = threadIdx.x;
  const int half = blockIdx.y;

  const float4* W4 = (const float4*)W_phi;
  #pragma unroll 4
  for (int it = 0; it < 32; ++it) {
    int f  = it * 256 + tid;
    int c  = f >> 4;
    int w4 = f & 15;
    float4 v = W4[c * 32 + half * 16 + w4];
    tbl[c * 32 + w4 * 2]     = bf16rne(v.x) | (bf16rne(v.y) << 16);
    tbl[c * 32 + w4 * 2 + 1] = bf16rne(v.z) | (bf16rne(v.w) << 16);
  }
  __syncthreads();

  const int rs  = tid >> 3;
  const int oc  = tid & 7;
  const int row = blockIdx.x * 32 + rs;
  const int* xrow = x + row * N_POS;

  float acc[8];
  #pragma unroll
  for (int e = 0; e < 8; ++e) acc[e] = 0.0f;

  for (int n0 = 0; n0 < N_POS; n0 += 4) {
    int4 xi = *(const int4*)(xrow + n0);
    int cc[4] = {xi.x, xi.y, xi.z, xi.w};
    #pragma unroll
    for (int qq = 0; qq < 4; ++qq) {
      uint4 t = *(const uint4*)(tbl + cc[qq] * 32 + oc * 4);
      acc[0] += bflo(t.x); acc[1] += bfhi(t.x);
      acc[2] += bflo(t.y); acc[3] += bfhi(t.y);
      acc[4] += bflo(t.z); acc[5] += bfhi(t.z);
      acc[6] += bflo(t.w); acc[7] += bfhi(t.w);
    }
  }

  const int pbase = half * 64 + oc * 8;
  uint4 st;
  st.x = bf16rne(acc[0]) | (bf16rne(acc[1]) << 16);
  st.y = bf16rne(acc[2]) | (bf16rne(acc[3]) << 16);
  st.z = bf16rne(acc[4]) | (bf16rne(acc[5]) << 16);
  st.w = bf16rne(acc[6]) | (bf16rne(acc[7]) << 16);
  *(uint4*)(u_bf + (size_t)row * PHI + pbase) = st;
}

// ---------------------------------------------------------------------------
// bf16 MFMA GEMM: C = act(A @ BT^T + bias). A: MxK bf16 row-major,
// BT: NxK bf16 row-major (pre-transposed). 64x64 tile, BK=32, 256 thr.
// Wave w computes rows [16w,16w+16) x 64 cols via 4x mfma_f32_16x16x32_bf16.
// LDS chunk XOR-swizzle kills the 8-way fragment-read bank conflict.
// ---------------------------------------------------------------------------
template<int RELU, int OUT_BF16>
__global__ __launch_bounds__(256) void gemm_mfma(
    const unsigned short* __restrict__ A, const unsigned short* __restrict__ BT,
    const float* __restrict__ bias, void* __restrict__ Cout, int K, int N) {
  __shared__ unsigned short As[64 * 32];
  __shared__ unsigned short Bs[64 * 32];
  const int tid = threadIdx.x;
  const int w = tid >> 6;
  const int l = tid & 63;
  const int bm = blockIdx.x * 64;
  const int bn = blockIdx.y * 64;

  // staging: thread t fills LDS chunk t (16B); global element chosen so that
  // chunk(row,q) = row*4 + (q ^ ((row>>1)&3))
  const int srow = tid >> 2;
  const int sq   = (tid & 3) ^ ((tid >> 3) & 3);
  const unsigned short* ga = A  + (size_t)(bm + srow) * K + sq * 8;
  const unsigned short* gb = BT + (size_t)(bn + srow) * K + sq * 8;

  const int r = l & 15;          // frag col (B) / row (A)
  const int q = l >> 4;          // k-octet
  const int sw = q ^ ((r >> 1) & 3);
  const int achunk = ((16 * w + r) * 4 + sw) * 8;

  f32x4 acc[4];
  #pragma unroll
  for (int j = 0; j < 4; ++j) acc[j] = (f32x4){0.f, 0.f, 0.f, 0.f};

  for (int k0 = 0; k0 < K; k0 += 32) {
    gload16(ga + k0, &As[tid * 8]);
    gload16(gb + k0, &Bs[tid * 8]);
    __syncthreads();
    bf16x8 af = *(const bf16x8*)&As[achunk];
    #pragma unroll
    for (int j = 0; j < 4; ++j) {
      bf16x8 bfr = *(const bf16x8*)&Bs[((16 * j + r) * 4 + sw) * 8];
      acc[j] = __builtin_amdgcn_mfma_f32_16x16x32_bf16(af, bfr, acc[j], 0, 0, 0);
    }
    __syncthreads();
  }

  // epilogue: C/D layout col=lane&15, row=(lane>>4)*4+reg
  #pragma unroll
  for (int j = 0; j < 4; ++j) {
    const int col = bn + 16 * j + r;
    const float bv = bias[col];
    #pragma unroll
    for (int reg = 0; reg < 4; ++reg) {
      const int rowi = bm + 16 * w + q * 4 + reg;
      float v = acc[j][reg] + bv;
      if (RELU) v = fmaxf(v, 0.0f);
      if (OUT_BF16)
        ((unsigned short*)Cout)[(size_t)rowi * N + col] = (unsigned short)bf16rne(v);
      else
        ((float*)Cout)[(size_t)rowi * N + col] = v;
    }
  }
}

// ---------------------------------------------------------------------------
// matvec: out[b] = dot(h2[b], W3) + b3. 64 blocks x 256 thr, 16 rows/wave.
// ---------------------------------------------------------------------------
__global__ __launch_bounds__(256) void matvec_out(
    const float* __restrict__ h2, const float* __restrict__ W3,
    const float* __restrict__ b3, float* __restrict__ out) {
  __shared__ float wv_s[H2D];
  const int tid = threadIdx.x;
  wv_s[tid] = W3[tid];
  __syncthreads();
  const int wave = tid >> 6, lane = tid & 63;
  const float b3v = b3[0];
  const float4 wv = *(const float4*)&wv_s[lane * 4];
  #pragma unroll 4
  for (int rr = 0; rr < 16; ++rr) {
    int row = (blockIdx.x * 4 + wave) * 16 + rr;
    float4 v = *(const float4*)(h2 + (size_t)row * H2D + lane * 4);
    float s = v.x * wv.x + v.y * wv.y + v.z * wv.z + v.w * wv.w;
    #pragma unroll
    for (int off = 32; off > 0; off >>= 1) s += __shfl_down(s, off, 64);
    if (lane == 0) out[row] = s + b3v;
  }
}

// ---------------------------------------------------------------------------
extern "C" void kernel_launch(void* const* d_in, const int* in_sizes, int n_in,
                              void* d_out, int out_size, void* d_ws, size_t ws_size,
                              hipStream_t stream) {
  const int*   x     = (const int*)  d_in[0];
  const float* W_phi = (const float*)d_in[1];
  const float* b_phi = (const float*)d_in[2];
  const float* W1    = (const float*)d_in[3];
  const float* b1    = (const float*)d_in[4];
  const float* W2    = (const float*)d_in[5];
  const float* b2    = (const float*)d_in[6];
  const float* W3    = (const float*)d_in[7];
  const float* b3    = (const float*)d_in[8];
  float* out = (float*)d_out;

  char* ws = (char*)d_ws;
  unsigned short* u_bf  = (unsigned short*)(ws);                          // 1 MB
  unsigned short* h1_bf = (unsigned short*)(ws + (1u << 20));             // 4 MB
  float*          h2    = (float*)         (ws + (5u << 20));             // 4 MB
  unsigned short* W1T   = (unsigned short*)(ws + (9u << 20));             // 128 KB
  unsigned short* W2T   = (unsigned short*)(ws + (9u << 20) + 131072);    // 256 KB
  float*          b1eff = (float*)         (ws + (9u << 20) + 393216);    // 2 KB

  prep<<<770, 256, 0, stream>>>(W1, W2, b_phi, b1, W1T, W2T, b1eff);
  gather_u<<<dim3(B_SZ / 32, 2), 256, 0, stream>>>(x, W_phi, u_bf);
  gemm_mfma<1, 1><<<dim3(B_SZ / 64, H1D / 64), 256, 0, stream>>>(
      u_bf, W1T, b1eff, h1_bf, PHI, H1D);
  gemm_mfma<1, 0><<<dim3(B_SZ / 64, H2D / 64), 256, 0, stream>>>(
      h1_bf, W2T, b2, h2, H1D, H2D);
  matvec_out<<<B_SZ / 64, 256, 0, stream>>>(h2, W3, b3, out);
}

// Round 3
// 103.256 us; speedup vs baseline: 1.7290x; 1.2274x over previous
//
#include <hip/hip_runtime.h>
#include <hip/hip_bf16.h>
#include <cstdint>

#define B_SZ  4096
#define N_POS 512
#define N_CLS 512
#define PHI   128
#define H1D   512
#define H2D   256

typedef short bf16x8 __attribute__((ext_vector_type(8)));
typedef float f32x4  __attribute__((ext_vector_type(4)));

__device__ __forceinline__ unsigned int bf16rne(float f) {
  unsigned int x = __float_as_uint(f);
  return (x + 0x7fffu + ((x >> 16) & 1u)) >> 16;
}

__device__ __forceinline__ void gload16(const void* g, void* l) {
  __builtin_amdgcn_global_load_lds(
      (const __attribute__((address_space(1))) unsigned int*)g,
      (__attribute__((address_space(3))) unsigned int*)l, 16, 0, 0);
}

// ---------------------------------------------------------------------------
// prep_hist: fused histogram + weight prep. grid 1282 x 256.
//  blocks 0..255    : Hist[b][c] = count of class c in x row b (bf16, exact)
//  blocks 256..511  : W1T[j][p]  = bf16(W1[p][j])          (512x128)
//  blocks 512..767  : Wphi_bf    = bf16(W_phi) row-major    (512x128)
//  blocks 768..1279 : W2T[n][k]  = bf16(W2[k][n])           (256x512)
//  blocks 1280..1281: b1eff[j]   = b1[j] + 512*(b_phi @ W1[:,j])  (fp32)
// ---------------------------------------------------------------------------
__global__ __launch_bounds__(256) void prep_hist(
    const int* __restrict__ x, const float* __restrict__ W_phi,
    const float* __restrict__ W1, const float* __restrict__ W2,
    const float* __restrict__ b_phi, const float* __restrict__ b1,
    unsigned short* __restrict__ Hist, unsigned short* __restrict__ W1T,
    unsigned short* __restrict__ Wphi_bf, unsigned short* __restrict__ W2T,
    float* __restrict__ b1eff) {
  __shared__ unsigned int hs[16 * 512];  // 32 KB
  const int b = blockIdx.x, tid = threadIdx.x;

  if (b < 256) {
    // ---- histogram: 16 rows per block, 16 threads per row ----
    uint4* hs4 = (uint4*)hs;
    #pragma unroll
    for (int i = 0; i < 8; ++i) hs4[tid * 8 + i] = make_uint4(0, 0, 0, 0);
    __syncthreads();
    const int row = tid >> 4;          // local row 0..15
    const int sub = tid & 15;          // position sub-range
    const int grow = b * 16 + row;
    const int* xp = x + (size_t)grow * N_POS + sub * 32;
    #pragma unroll
    for (int i = 0; i < 8; ++i) {
      int4 c = *(const int4*)(xp + i * 4);
      atomicAdd(&hs[row * 512 + c.x], 1u);
      atomicAdd(&hs[row * 512 + c.y], 1u);
      atomicAdd(&hs[row * 512 + c.z], 1u);
      atomicAdd(&hs[row * 512 + c.w], 1u);
    }
    __syncthreads();
    // writeback: thread covers 32 consecutive bins of its row, bf16-pack
    const unsigned int* src = hs + row * 512 + sub * 32;
    unsigned short* dst = Hist + (size_t)grow * 512 + sub * 32;
    #pragma unroll
    for (int i = 0; i < 4; ++i) {
      uint4 a = *(const uint4*)(src + i * 8);
      uint4 bq = *(const uint4*)(src + i * 8 + 4);
      uint4 o;
      o.x = bf16rne((float)a.x)  | (bf16rne((float)a.y)  << 16);
      o.y = bf16rne((float)a.z)  | (bf16rne((float)a.w)  << 16);
      o.z = bf16rne((float)bq.x) | (bf16rne((float)bq.y) << 16);
      o.w = bf16rne((float)bq.z) | (bf16rne((float)bq.w) << 16);
      *(uint4*)(dst + i * 8) = o;
    }
  } else if (b < 512) {
    int o = (b - 256) * 256 + tid;
    int j = o >> 7, p = o & 127;
    W1T[o] = (unsigned short)bf16rne(W1[p * 512 + j]);
  } else if (b < 768) {
    int o = (b - 512) * 256 + tid;
    Wphi_bf[o] = (unsigned short)bf16rne(W_phi[o]);
  } else if (b < 1280) {
    int o = (b - 768) * 256 + tid;
    int n = o >> 9, k = o & 511;
    W2T[o] = (unsigned short)bf16rne(W2[k * 256 + n]);
  } else {
    int j = (b - 1280) * 256 + tid;
    float a = 0.0f;
    #pragma unroll 8
    for (int p = 0; p < PHI; ++p) a += b_phi[p] * W1[p * 512 + j];
    b1eff[j] = b1[j] + 512.0f * a;
  }
}

// ---------------------------------------------------------------------------
// bf16 MFMA GEMM: C = act(A @ BT^T [+ bias]). A: MxK bf16, BT: NxK bf16.
// 64x64 tile, BK=32, 256 thr, 4x mfma_f32_16x16x32_bf16 per wave per iter.
// ---------------------------------------------------------------------------
template<int RELU, int OUT_BF16, int BIAS>
__global__ __launch_bounds__(256) void gemm_mfma(
    const unsigned short* __restrict__ A, const unsigned short* __restrict__ BT,
    const float* __restrict__ bias, void* __restrict__ Cout, int K, int N) {
  __shared__ unsigned short As[64 * 32];
  __shared__ unsigned short Bs[64 * 32];
  const int tid = threadIdx.x;
  const int w = tid >> 6;
  const int l = tid & 63;
  const int bm = blockIdx.x * 64;
  const int bn = blockIdx.y * 64;

  const int srow = tid >> 2;
  const int sq   = (tid & 3) ^ ((tid >> 3) & 3);
  const unsigned short* ga = A  + (size_t)(bm + srow) * K + sq * 8;
  const unsigned short* gb = BT + (size_t)(bn + srow) * K + sq * 8;

  const int r = l & 15;
  const int q = l >> 4;
  const int sw = q ^ ((r >> 1) & 3);
  const int achunk = ((16 * w + r) * 4 + sw) * 8;

  f32x4 acc[4];
  #pragma unroll
  for (int j = 0; j < 4; ++j) acc[j] = (f32x4){0.f, 0.f, 0.f, 0.f};

  for (int k0 = 0; k0 < K; k0 += 32) {
    gload16(ga + k0, &As[tid * 8]);
    gload16(gb + k0, &Bs[tid * 8]);
    __syncthreads();
    bf16x8 af = *(const bf16x8*)&As[achunk];
    #pragma unroll
    for (int j = 0; j < 4; ++j) {
      bf16x8 bfr = *(const bf16x8*)&Bs[((16 * j + r) * 4 + sw) * 8];
      acc[j] = __builtin_amdgcn_mfma_f32_16x16x32_bf16(af, bfr, acc[j], 0, 0, 0);
    }
    __syncthreads();
  }

  #pragma unroll
  for (int j = 0; j < 4; ++j) {
    const int col = bn + 16 * j + r;
    const float bv = BIAS ? bias[col] : 0.0f;
    #pragma unroll
    for (int reg = 0; reg < 4; ++reg) {
      const int rowi = bm + 16 * w + q * 4 + reg;
      float v = acc[j][reg] + bv;
      if (RELU) v = fmaxf(v, 0.0f);
      if (OUT_BF16)
        ((unsigned short*)Cout)[(size_t)rowi * N + col] = (unsigned short)bf16rne(v);
      else
        ((float*)Cout)[(size_t)rowi * N + col] = v;
    }
  }
}

// ---------------------------------------------------------------------------
// gemm2_out: out[b] = relu(h1[b]@W2 + b2) @ W3 + b3, fused.
// A: 4096x512 bf16 (h1), BT: W2T 256x512 bf16. 16 rows/block, 256 blocks.
// Wave w handles j-tiles 4w..4w+3 (cols 64w..64w+63); h2 never hits memory.
// ---------------------------------------------------------------------------
__global__ __launch_bounds__(256) void gemm2_out(
    const unsigned short* __restrict__ A, const unsigned short* __restrict__ BT,
    const float* __restrict__ b2, const float* __restrict__ W3,
    const float* __restrict__ b3, float* __restrict__ out) {
  __shared__ unsigned short Bs[256 * 32];  // 16 KB
  __shared__ unsigned short As[16 * 32];   // 1 KB
  __shared__ float red[4][16];
  const int tid = threadIdx.x;
  const int w = tid >> 6;
  const int l = tid & 63;
  const int r = l & 15;
  const int q = l >> 4;
  const int sw = q ^ ((r >> 1) & 3);
  const int bm = blockIdx.x * 16;

  f32x4 acc[4];
  #pragma unroll
  for (int j = 0; j < 4; ++j) acc[j] = (f32x4){0.f, 0.f, 0.f, 0.f};

  for (int k0 = 0; k0 < 512; k0 += 32) {
    if (tid < 64) {
      int srow = tid >> 2;
      int gq = (tid & 3) ^ ((tid >> 3) & 3);
      gload16(A + (size_t)(bm + srow) * 512 + k0 + gq * 8, &As[tid * 8]);
    }
    #pragma unroll
    for (int i = 0; i < 4; ++i) {
      int d = tid + 256 * i;
      int srow = d >> 2;
      int gq = (d & 3) ^ ((d >> 3) & 3);
      gload16(BT + (size_t)srow * 512 + k0 + gq * 8, &Bs[d * 8]);
    }
    __syncthreads();
    bf16x8 af = *(const bf16x8*)&As[(r * 4 + sw) * 8];
    #pragma unroll
    for (int jj = 0; jj < 4; ++jj) {
      int j = w * 4 + jj;
      bf16x8 bfr = *(const bf16x8*)&Bs[((16 * j + r) * 4 + sw) * 8];
      acc[jj] = __builtin_amdgcn_mfma_f32_16x16x32_bf16(af, bfr, acc[jj], 0, 0, 0);
    }
    __syncthreads();
  }

  // epilogue: relu(h2)+bias, dot with W3 per lane, reduce over the 16 r-lanes
  float part[4] = {0.f, 0.f, 0.f, 0.f};
  #pragma unroll
  for (int jj = 0; jj < 4; ++jj) {
    int col = 16 * (w * 4 + jj) + r;
    float bv = b2[col];
    float w3 = W3[col];
    #pragma unroll
    for (int reg = 0; reg < 4; ++reg) {
      float v = fmaxf(acc[jj][reg] + bv, 0.0f);
      part[reg] += v * w3;
    }
  }
  #pragma unroll
  for (int off = 1; off < 16; off <<= 1) {
    #pragma unroll
    for (int reg = 0; reg < 4; ++reg)
      part[reg] += __shfl_xor(part[reg], off, 64);
  }
  if (r == 0) {
    #pragma unroll
    for (int reg = 0; reg < 4; ++reg) red[w][q * 4 + reg] = part[reg];
  }
  __syncthreads();
  if (tid < 16)
    out[bm + tid] = red[0][tid] + red[1][tid] + red[2][tid] + red[3][tid] + b3[0];
}

// ---------------------------------------------------------------------------
extern "C" void kernel_launch(void* const* d_in, const int* in_sizes, int n_in,
                              void* d_out, int out_size, void* d_ws, size_t ws_size,
                              hipStream_t stream) {
  const int*   x     = (const int*)  d_in[0];
  const float* W_phi = (const float*)d_in[1];
  const float* b_phi = (const float*)d_in[2];
  const float* W1    = (const float*)d_in[3];
  const float* b1    = (const float*)d_in[4];
  const float* W2    = (const float*)d_in[5];
  const float* b2    = (const float*)d_in[6];
  const float* W3    = (const float*)d_in[7];
  const float* b3    = (const float*)d_in[8];
  float* out = (float*)d_out;

  char* ws = (char*)d_ws;
  unsigned short* Hist    = (unsigned short*)(ws);                       // 4 MB
  unsigned short* h1_bf   = (unsigned short*)(ws + (4u << 20));          // 4 MB
  unsigned short* WfT     = (unsigned short*)(ws + (8u << 20));          // 512 KB
  unsigned short* W1T     = (unsigned short*)(ws + (8u << 20) + 524288); // 128 KB
  unsigned short* Wphi_bf = (unsigned short*)(ws + (8u << 20) + 655360); // 128 KB
  unsigned short* W2T     = (unsigned short*)(ws + (8u << 20) + 786432); // 256 KB
  float*          b1eff   = (float*)         (ws + (9u << 20));          // 2 KB

  prep_hist<<<1282, 256, 0, stream>>>(x, W_phi, W1, W2, b_phi, b1,
                                      Hist, W1T, Wphi_bf, W2T, b1eff);
  // WfT[j][c] = dot(W1T[j,:], Wphi_bf[c,:])  (= (W_phi @ W1)^T), 512x512
  gemm_mfma<0, 1, 0><<<dim3(8, 8), 256, 0, stream>>>(
      W1T, Wphi_bf, nullptr, WfT, PHI, H1D);
  // h1 = relu(Hist @ WfT^T + b1eff), 4096x512, K=512
  gemm_mfma<1, 1, 1><<<dim3(B_SZ / 64, H1D / 64), 256, 0, stream>>>(
      Hist, WfT, b1eff, h1_bf, N_CLS, H1D);
  // out = relu(h1 @ W2 + b2) @ W3 + b3, fused
  gemm2_out<<<B_SZ / 16, 256, 0, stream>>>(h1_bf, W2T, b2, W3, b3, out);
}

// Round 4
// 101.461 us; speedup vs baseline: 1.7596x; 1.0177x over previous
//
#include <hip/hip_runtime.h>
#include <hip/hip_bf16.h>
#include <cstdint>

#define B_SZ  4096
#define N_POS 512
#define N_CLS 512
#define PHI   128
#define H1D   512
#define H2D   256

typedef short bf16x8 __attribute__((ext_vector_type(8)));
typedef float f32x4  __attribute__((ext_vector_type(4)));

__device__ __forceinline__ unsigned int bf16rne(float f) {
  unsigned int x = __float_as_uint(f);
  return (x + 0x7fffu + ((x >> 16) & 1u)) >> 16;
}

__device__ __forceinline__ void gload16(const void* g, void* l) {
  __builtin_amdgcn_global_load_lds(
      (const __attribute__((address_space(1))) unsigned int*)g,
      (__attribute__((address_space(3))) unsigned int*)l, 16, 0, 0);
}

// ---------------------------------------------------------------------------
// prep: fused histogram + WfT GEMM + weight prep. grid 834 x 256.
//  blocks 0..255   : Hist[b][c] = count of class c in x row b (bf16, exact)
//  blocks 256..319 : WfT[j][c] = (W_phi @ W1)^T, bf16, MFMA direct from fp32
//  blocks 320..831 : W2T[n][k] = bf16(W2[k][n])  (256x512)
//  blocks 832..833 : b1eff[j]  = b1[j] + 512*(b_phi @ W1[:,j])  (fp32)
// ---------------------------------------------------------------------------
__global__ __launch_bounds__(256) void prep(
    const int* __restrict__ x, const float* __restrict__ W_phi,
    const float* __restrict__ W1, const float* __restrict__ W2,
    const float* __restrict__ b_phi, const float* __restrict__ b1,
    unsigned short* __restrict__ Hist, unsigned short* __restrict__ WfT,
    unsigned short* __restrict__ W2T, float* __restrict__ b1eff) {
  __shared__ unsigned int hs[16 * 512];  // 32 KB (hist blocks only)
  const int b = blockIdx.x, tid = threadIdx.x;

  if (b < 256) {
    // ---- histogram: 16 rows per block, 16 threads per row ----
    uint4* hs4 = (uint4*)hs;
    #pragma unroll
    for (int i = 0; i < 8; ++i) hs4[tid * 8 + i] = make_uint4(0, 0, 0, 0);
    __syncthreads();
    const int row = tid >> 4;
    const int sub = tid & 15;
    const int grow = b * 16 + row;
    const int* xp = x + (size_t)grow * N_POS + sub * 32;
    #pragma unroll
    for (int i = 0; i < 8; ++i) {
      int4 c = *(const int4*)(xp + i * 4);
      atomicAdd(&hs[row * 512 + c.x], 1u);
      atomicAdd(&hs[row * 512 + c.y], 1u);
      atomicAdd(&hs[row * 512 + c.z], 1u);
      atomicAdd(&hs[row * 512 + c.w], 1u);
    }
    __syncthreads();
    const unsigned int* src = hs + row * 512 + sub * 32;
    unsigned short* dst = Hist + (size_t)grow * 512 + sub * 32;
    #pragma unroll
    for (int i = 0; i < 4; ++i) {
      uint4 a = *(const uint4*)(src + i * 8);
      uint4 bq = *(const uint4*)(src + i * 8 + 4);
      uint4 o;
      o.x = bf16rne((float)a.x)  | (bf16rne((float)a.y)  << 16);
      o.y = bf16rne((float)a.z)  | (bf16rne((float)a.w)  << 16);
      o.z = bf16rne((float)bq.x) | (bf16rne((float)bq.y) << 16);
      o.w = bf16rne((float)bq.z) | (bf16rne((float)bq.w) << 16);
      *(uint4*)(dst + i * 8) = o;
    }
  } else if (b < 320) {
    // ---- WfT tile (64 j-rows x 64 c-cols), K=PHI=128, direct fp32->bf16 ----
    const int wb = b - 256;
    const int bm = (wb & 7) * 64;    // j tile
    const int bn = (wb >> 3) * 64;   // c tile
    const int w = tid >> 6, l = tid & 63;
    const int r = l & 15, q = l >> 4;

    f32x4 acc[4];
    #pragma unroll
    for (int j = 0; j < 4; ++j) acc[j] = (f32x4){0.f, 0.f, 0.f, 0.f};

    const float* acol = W1 + (bm + 16 * w + r);   // + k*512
    #pragma unroll
    for (int k0 = 0; k0 < PHI; k0 += 32) {
      bf16x8 af;
      #pragma unroll
      for (int i = 0; i < 8; ++i)
        af[i] = (short)bf16rne(acol[(size_t)(k0 + q * 8 + i) * H1D]);
      #pragma unroll
      for (int jj = 0; jj < 4; ++jj) {
        const float* bp = W_phi + (size_t)(bn + 16 * jj + r) * PHI + k0 + q * 8;
        bf16x8 bfr;
        #pragma unroll
        for (int i = 0; i < 8; ++i) bfr[i] = (short)bf16rne(bp[i]);
        acc[jj] = __builtin_amdgcn_mfma_f32_16x16x32_bf16(af, bfr, acc[jj], 0, 0, 0);
      }
    }
    #pragma unroll
    for (int jj = 0; jj < 4; ++jj) {
      const int col = bn + 16 * jj + r;
      #pragma unroll
      for (int reg = 0; reg < 4; ++reg) {
        const int rowi = bm + 16 * w + q * 4 + reg;
        WfT[(size_t)rowi * N_CLS + col] = (unsigned short)bf16rne(acc[jj][reg]);
      }
    }
  } else if (b < 832) {
    int o = (b - 320) * 256 + tid;
    int n = o >> 9, k = o & 511;
    W2T[o] = (unsigned short)bf16rne(W2[k * 256 + n]);
  } else {
    int j = (b - 832) * 256 + tid;
    float a = 0.0f;
    #pragma unroll 8
    for (int p = 0; p < PHI; ++p) a += b_phi[p] * W1[p * 512 + j];
    b1eff[j] = b1[j] + 512.0f * a;
  }
}

// ---------------------------------------------------------------------------
// bf16 MFMA GEMM: C = act(A @ BT^T + bias). A: MxK bf16, BT: NxK bf16.
// 64x64 tile, BK=32, 256 thr, 4x mfma_f32_16x16x32_bf16 per wave per iter.
// ---------------------------------------------------------------------------
template<int RELU, int OUT_BF16, int BIAS>
__global__ __launch_bounds__(256) void gemm_mfma(
    const unsigned short* __restrict__ A, const unsigned short* __restrict__ BT,
    const float* __restrict__ bias, void* __restrict__ Cout, int K, int N) {
  __shared__ unsigned short As[64 * 32];
  __shared__ unsigned short Bs[64 * 32];
  const int tid = threadIdx.x;
  const int w = tid >> 6;
  const int l = tid & 63;
  const int bm = blockIdx.x * 64;
  const int bn = blockIdx.y * 64;

  const int srow = tid >> 2;
  const int sq   = (tid & 3) ^ ((tid >> 3) & 3);
  const unsigned short* ga = A  + (size_t)(bm + srow) * K + sq * 8;
  const unsigned short* gb = BT + (size_t)(bn + srow) * K + sq * 8;

  const int r = l & 15;
  const int q = l >> 4;
  const int sw = q ^ ((r >> 1) & 3);
  const int achunk = ((16 * w + r) * 4 + sw) * 8;

  f32x4 acc[4];
  #pragma unroll
  for (int j = 0; j < 4; ++j) acc[j] = (f32x4){0.f, 0.f, 0.f, 0.f};

  for (int k0 = 0; k0 < K; k0 += 32) {
    gload16(ga + k0, &As[tid * 8]);
    gload16(gb + k0, &Bs[tid * 8]);
    __syncthreads();
    bf16x8 af = *(const bf16x8*)&As[achunk];
    #pragma unroll
    for (int j = 0; j < 4; ++j) {
      bf16x8 bfr = *(const bf16x8*)&Bs[((16 * j + r) * 4 + sw) * 8];
      acc[j] = __builtin_amdgcn_mfma_f32_16x16x32_bf16(af, bfr, acc[j], 0, 0, 0);
    }
    __syncthreads();
  }

  #pragma unroll
  for (int j = 0; j < 4; ++j) {
    const int col = bn + 16 * j + r;
    const float bv = BIAS ? bias[col] : 0.0f;
    #pragma unroll
    for (int reg = 0; reg < 4; ++reg) {
      const int rowi = bm + 16 * w + q * 4 + reg;
      float v = acc[j][reg] + bv;
      if (RELU) v = fmaxf(v, 0.0f);
      if (OUT_BF16)
        ((unsigned short*)Cout)[(size_t)rowi * N + col] = (unsigned short)bf16rne(v);
      else
        ((float*)Cout)[(size_t)rowi * N + col] = v;
    }
  }
}

// ---------------------------------------------------------------------------
// gemm2_out: out[b] = relu(h1[b]@W2 + b2) @ W3 + b3, fused.
// A: 4096x512 bf16 (h1), BT: W2T 256x512 bf16. 16 rows/block, 256 blocks.
// ---------------------------------------------------------------------------
__global__ __launch_bounds__(256) void gemm2_out(
    const unsigned short* __restrict__ A, const unsigned short* __restrict__ BT,
    const float* __restrict__ b2, const float* __restrict__ W3,
    const float* __restrict__ b3, float* __restrict__ out) {
  __shared__ unsigned short Bs[256 * 32];  // 16 KB
  __shared__ unsigned short As[16 * 32];   // 1 KB
  __shared__ float red[4][16];
  const int tid = threadIdx.x;
  const int w = tid >> 6;
  const int l = tid & 63;
  const int r = l & 15;
  const int q = l >> 4;
  const int sw = q ^ ((r >> 1) & 3);
  const int bm = blockIdx.x * 16;

  f32x4 acc[4];
  #pragma unroll
  for (int j = 0; j < 4; ++j) acc[j] = (f32x4){0.f, 0.f, 0.f, 0.f};

  for (int k0 = 0; k0 < 512; k0 += 32) {
    if (tid < 64) {
      int srow = tid >> 2;
      int gq = (tid & 3) ^ ((tid >> 3) & 3);
      gload16(A + (size_t)(bm + srow) * 512 + k0 + gq * 8, &As[tid * 8]);
    }
    #pragma unroll
    for (int i = 0; i < 4; ++i) {
      int d = tid + 256 * i;
      int srow = d >> 2;
      int gq = (d & 3) ^ ((d >> 3) & 3);
      gload16(BT + (size_t)srow * 512 + k0 + gq * 8, &Bs[d * 8]);
    }
    __syncthreads();
    bf16x8 af = *(const bf16x8*)&As[(r * 4 + sw) * 8];
    #pragma unroll
    for (int jj = 0; jj < 4; ++jj) {
      int j = w * 4 + jj;
      bf16x8 bfr = *(const bf16x8*)&Bs[((16 * j + r) * 4 + sw) * 8];
      acc[jj] = __builtin_amdgcn_mfma_f32_16x16x32_bf16(af, bfr, acc[jj], 0, 0, 0);
    }
    __syncthreads();
  }

  float part[4] = {0.f, 0.f, 0.f, 0.f};
  #pragma unroll
  for (int jj = 0; jj < 4; ++jj) {
    int col = 16 * (w * 4 + jj) + r;
    float bv = b2[col];
    float w3 = W3[col];
    #pragma unroll
    for (int reg = 0; reg < 4; ++reg) {
      float v = fmaxf(acc[jj][reg] + bv, 0.0f);
      part[reg] += v * w3;
    }
  }
  #pragma unroll
  for (int off = 1; off < 16; off <<= 1) {
    #pragma unroll
    for (int reg = 0; reg < 4; ++reg)
      part[reg] += __shfl_xor(part[reg], off, 64);
  }
  if (r == 0) {
    #pragma unroll
    for (int reg = 0; reg < 4; ++reg) red[w][q * 4 + reg] = part[reg];
  }
  __syncthreads();
  if (tid < 16)
    out[bm + tid] = red[0][tid] + red[1][tid] + red[2][tid] + red[3][tid] + b3[0];
}

// ---------------------------------------------------------------------------
extern "C" void kernel_launch(void* const* d_in, const int* in_sizes, int n_in,
                              void* d_out, int out_size, void* d_ws, size_t ws_size,
                              hipStream_t stream) {
  const int*   x     = (const int*)  d_in[0];
  const float* W_phi = (const float*)d_in[1];
  const float* b_phi = (const float*)d_in[2];
  const float* W1    = (const float*)d_in[3];
  const float* b1    = (const float*)d_in[4];
  const float* W2    = (const float*)d_in[5];
  const float* b2    = (const float*)d_in[6];
  const float* W3    = (const float*)d_in[7];
  const float* b3    = (const float*)d_in[8];
  float* out = (float*)d_out;

  char* ws = (char*)d_ws;
  unsigned short* Hist  = (unsigned short*)(ws);                        // 4 MB
  unsigned short* h1_bf = (unsigned short*)(ws + (4u << 20));           // 4 MB
  unsigned short* WfT   = (unsigned short*)(ws + (8u << 20));           // 512 KB
  unsigned short* W2T   = (unsigned short*)(ws + (8u << 20) + 524288);  // 256 KB
  float*          b1eff = (float*)         (ws + (9u << 20));           // 2 KB

  prep<<<834, 256, 0, stream>>>(x, W_phi, W1, W2, b_phi, b1,
                                Hist, WfT, W2T, b1eff);
  // h1 = relu(Hist @ WfT^T + b1eff), 4096x512, K=512
  gemm_mfma<1, 1, 1><<<dim3(B_SZ / 64, H1D / 64), 256, 0, stream>>>(
      Hist, WfT, b1eff, h1_bf, N_CLS, H1D);
  // out = relu(h1 @ W2 + b2) @ W3 + b3, fused
  gemm2_out<<<B_SZ / 16, 256, 0, stream>>>(h1_bf, W2T, b2, W3, b3, out);
}

// Round 5
// 97.171 us; speedup vs baseline: 1.8373x; 1.0441x over previous
//
#include <hip/hip_runtime.h>
#include <hip/hip_bf16.h>
#include <cstdint>

#define B_SZ  4096
#define N_POS 512
#define N_CLS 512
#define PHI   128
#define H1D   512
#define H2D   256

#define HS 520   // hist/h1 LDS row stride in bf16 (512+8: bank-conflict-free)
#define US 136   // u LDS row stride in bf16 (128+8)

typedef short bf16x8 __attribute__((ext_vector_type(8)));
typedef float f32x4  __attribute__((ext_vector_type(4)));

__device__ __forceinline__ unsigned int bf16rne(float f) {
  unsigned int x = __float_as_uint(f);
  return (x + 0x7fffu + ((x >> 16) & 1u)) >> 16;
}

// ---------------------------------------------------------------------------
// prep: bf16 transposed weights + fp32 effective bias. grid 1026 x 256.
//  blocks 0..255    : WphiT[n][c] = bf16(W_phi[c][n])   (128 x 512)
//  blocks 256..511  : W1T[j][p]   = bf16(W1[p][j])      (512 x 128)
//  blocks 512..1023 : W2T[n][k]   = bf16(W2[k][n])      (256 x 512)
//  blocks 1024..1025: b1eff[j]    = b1[j] + 512*(b_phi @ W1[:,j])  (fp32)
// ---------------------------------------------------------------------------
__global__ __launch_bounds__(256) void prep(
    const float* __restrict__ W_phi, const float* __restrict__ W1,
    const float* __restrict__ W2, const float* __restrict__ b_phi,
    const float* __restrict__ b1,
    unsigned short* __restrict__ WphiT, unsigned short* __restrict__ W1T,
    unsigned short* __restrict__ W2T, float* __restrict__ b1eff) {
  const int b = blockIdx.x, tid = threadIdx.x;
  if (b < 256) {
    int o = b * 256 + tid;
    int n = o >> 9, c = o & 511;
    WphiT[o] = (unsigned short)bf16rne(W_phi[c * PHI + n]);
  } else if (b < 512) {
    int o = (b - 256) * 256 + tid;
    int j = o >> 7, p = o & 127;
    W1T[o] = (unsigned short)bf16rne(W1[p * H1D + j]);
  } else if (b < 1024) {
    int o = (b - 512) * 256 + tid;
    int n = o >> 9, k = o & 511;
    W2T[o] = (unsigned short)bf16rne(W2[k * H2D + n]);
  } else {
    int j = (b - 1024) * 256 + tid;
    float a = 0.0f;
    #pragma unroll 8
    for (int p = 0; p < PHI; ++p) a += b_phi[p] * W1[p * H1D + j];
    b1eff[j] = b1[j] + 512.0f * a;
  }
}

// ---------------------------------------------------------------------------
// fused: per block of 16 batch rows (256 blocks, 256 threads):
//   hist (LDS atomics) -> u = Hist@WphiT^T -> h1 = relu(u@W1T^T + b1eff)
//   -> h2 = relu(h1@W2T^T + b2) -> out = h2@W3 + b3
// Hist/u/h1 live only in LDS. B-fragments stream 16B/lane from L2-resident
// transposed bf16 weights. MFMA 16x16x32, A-frag: m=lane&15, k=(lane>>4)*8+i;
// C/D: col=lane&15, row=(lane>>4)*4+reg.
// ---------------------------------------------------------------------------
__global__ __launch_bounds__(256) void fused(
    const int* __restrict__ x,
    const unsigned short* __restrict__ WphiT,
    const unsigned short* __restrict__ W1T,
    const unsigned short* __restrict__ W2T,
    const float* __restrict__ b1eff, const float* __restrict__ b2,
    const float* __restrict__ W3, const float* __restrict__ b3,
    float* __restrict__ out) {
  __shared__ unsigned int   hs[16 * 512];       // 32 KB
  __shared__ unsigned short hist_bf[16 * HS];   // 16.25 KB
  __shared__ unsigned short u_bf[16 * US];      // 4.25 KB
  __shared__ unsigned short h1_bf[16 * HS];     // 16.25 KB
  __shared__ float red[4][16];

  const int tid = threadIdx.x;
  const int w = tid >> 6, l = tid & 63;
  const int r = l & 15, q = l >> 4;
  const int bm = blockIdx.x * 16;

  // ---- phase 0: histogram of 16 rows ----
  uint4* hs4 = (uint4*)hs;
  #pragma unroll
  for (int i = 0; i < 8; ++i) hs4[tid * 8 + i] = make_uint4(0, 0, 0, 0);
  __syncthreads();
  {
    const int row = tid >> 4, sub = tid & 15;
    const int* xp = x + (size_t)(bm + row) * N_POS + sub * 32;
    #pragma unroll
    for (int i = 0; i < 8; ++i) {
      int4 c = *(const int4*)(xp + i * 4);
      atomicAdd(&hs[row * 512 + c.x], 1u);
      atomicAdd(&hs[row * 512 + c.y], 1u);
      atomicAdd(&hs[row * 512 + c.z], 1u);
      atomicAdd(&hs[row * 512 + c.w], 1u);
    }
  }
  __syncthreads();
  {
    // counts <= 256 always -> bf16 exact
    const int row = tid >> 4, sub = tid & 15;
    const unsigned int* src = hs + row * 512 + sub * 32;
    unsigned short* dst = hist_bf + row * HS + sub * 32;
    #pragma unroll
    for (int i = 0; i < 4; ++i) {
      uint4 a = *(const uint4*)(src + i * 8);
      uint4 bq = *(const uint4*)(src + i * 8 + 4);
      uint4 o;
      o.x = bf16rne((float)a.x)  | (bf16rne((float)a.y)  << 16);
      o.y = bf16rne((float)a.z)  | (bf16rne((float)a.w)  << 16);
      o.z = bf16rne((float)bq.x) | (bf16rne((float)bq.y) << 16);
      o.w = bf16rne((float)bq.z) | (bf16rne((float)bq.w) << 16);
      *(uint4*)(dst + i * 8) = o;
    }
  }
  __syncthreads();

  // ---- phase 1: u = Hist @ WphiT^T  (K=512, N=128; wave w -> cols 32w..32w+31)
  f32x4 accu[2];
  accu[0] = (f32x4){0.f, 0.f, 0.f, 0.f};
  accu[1] = (f32x4){0.f, 0.f, 0.f, 0.f};
  #pragma unroll 4
  for (int k0 = 0; k0 < N_CLS; k0 += 32) {
    bf16x8 af = *(const bf16x8*)&hist_bf[r * HS + k0 + q * 8];
    #pragma unroll
    for (int tt = 0; tt < 2; ++tt) {
      bf16x8 bfr = *(const bf16x8*)(WphiT + (size_t)(32 * w + 16 * tt + r) * N_CLS + k0 + q * 8);
      accu[tt] = __builtin_amdgcn_mfma_f32_16x16x32_bf16(af, bfr, accu[tt], 0, 0, 0);
    }
  }
  #pragma unroll
  for (int tt = 0; tt < 2; ++tt)
    #pragma unroll
    for (int reg = 0; reg < 4; ++reg)
      u_bf[(q * 4 + reg) * US + 32 * w + 16 * tt + r] =
          (unsigned short)bf16rne(accu[tt][reg]);
  __syncthreads();

  // ---- phase 2: h1 = relu(u @ W1T^T + b1eff)  (K=128, N=512; wave w -> cols 128w..)
  f32x4 acc1[8];
  #pragma unroll
  for (int j = 0; j < 8; ++j) acc1[j] = (f32x4){0.f, 0.f, 0.f, 0.f};
  #pragma unroll
  for (int k0 = 0; k0 < PHI; k0 += 32) {
    bf16x8 af = *(const bf16x8*)&u_bf[r * US + k0 + q * 8];
    #pragma unroll
    for (int tt = 0; tt < 8; ++tt) {
      bf16x8 bfr = *(const bf16x8*)(W1T + (size_t)(128 * w + 16 * tt + r) * PHI + k0 + q * 8);
      acc1[tt] = __builtin_amdgcn_mfma_f32_16x16x32_bf16(af, bfr, acc1[tt], 0, 0, 0);
    }
  }
  #pragma unroll
  for (int tt = 0; tt < 8; ++tt) {
    const int col = 128 * w + 16 * tt + r;
    const float bv = b1eff[col];
    #pragma unroll
    for (int reg = 0; reg < 4; ++reg) {
      float v = fmaxf(acc1[tt][reg] + bv, 0.0f);
      h1_bf[(q * 4 + reg) * HS + col] = (unsigned short)bf16rne(v);
    }
  }
  __syncthreads();

  // ---- phase 3: h2 = relu(h1 @ W2T^T + b2); out = h2 @ W3 + b3
  f32x4 acc2[4];
  #pragma unroll
  for (int j = 0; j < 4; ++j) acc2[j] = (f32x4){0.f, 0.f, 0.f, 0.f};
  #pragma unroll 4
  for (int k0 = 0; k0 < H1D; k0 += 32) {
    bf16x8 af = *(const bf16x8*)&h1_bf[r * HS + k0 + q * 8];
    #pragma unroll
    for (int tt = 0; tt < 4; ++tt) {
      bf16x8 bfr = *(const bf16x8*)(W2T + (size_t)(64 * w + 16 * tt + r) * H1D + k0 + q * 8);
      acc2[tt] = __builtin_amdgcn_mfma_f32_16x16x32_bf16(af, bfr, acc2[tt], 0, 0, 0);
    }
  }
  float part[4] = {0.f, 0.f, 0.f, 0.f};
  #pragma unroll
  for (int tt = 0; tt < 4; ++tt) {
    const int col = 64 * w + 16 * tt + r;
    const float bv = b2[col];
    const float w3 = W3[col];
    #pragma unroll
    for (int reg = 0; reg < 4; ++reg)
      part[reg] += fmaxf(acc2[tt][reg] + bv, 0.0f) * w3;
  }
  #pragma unroll
  for (int off = 1; off < 16; off <<= 1)
    #pragma unroll
    for (int reg = 0; reg < 4; ++reg)
      part[reg] += __shfl_xor(part[reg], off, 64);
  if (r == 0)
    #pragma unroll
    for (int reg = 0; reg < 4; ++reg) red[w][q * 4 + reg] = part[reg];
  __syncthreads();
  if (tid < 16)
    out[bm + tid] = red[0][tid] + red[1][tid] + red[2][tid] + red[3][tid] + b3[0];
}

// ---------------------------------------------------------------------------
extern "C" void kernel_launch(void* const* d_in, const int* in_sizes, int n_in,
                              void* d_out, int out_size, void* d_ws, size_t ws_size,
                              hipStream_t stream) {
  const int*   x     = (const int*)  d_in[0];
  const float* W_phi = (const float*)d_in[1];
  const float* b_phi = (const float*)d_in[2];
  const float* W1    = (const float*)d_in[3];
  const float* b1    = (const float*)d_in[4];
  const float* W2    = (const float*)d_in[5];
  const float* b2    = (const float*)d_in[6];
  const float* W3    = (const float*)d_in[7];
  const float* b3    = (const float*)d_in[8];
  float* out = (float*)d_out;

  char* ws = (char*)d_ws;
  unsigned short* WphiT = (unsigned short*)(ws);            // 128 KB
  unsigned short* W1T   = (unsigned short*)(ws + 131072);   // 128 KB
  unsigned short* W2T   = (unsigned short*)(ws + 262144);   // 256 KB
  float*          b1eff = (float*)         (ws + 524288);   // 2 KB

  prep<<<1026, 256, 0, stream>>>(W_phi, W1, W2, b_phi, b1,
                                 WphiT, W1T, W2T, b1eff);
  fused<<<B_SZ / 16, 256, 0, stream>>>(x, WphiT, W1T, W2T,
                                       b1eff, b2, W3, b3, out);
}

// Round 6
// 95.421 us; speedup vs baseline: 1.8710x; 1.0183x over previous
//
#include <hip/hip_runtime.h>
#include <hip/hip_bf16.h>
#include <cstdint>

#define B_SZ  4096
#define N_POS 512
#define N_CLS 512
#define PHI   128
#define H1D   512
#define H2D   256

#define HS 520   // hist/h1 LDS row stride in bf16 (512+8: bank-conflict-free)
#define US 136   // u LDS row stride in bf16 (128+8)

typedef short bf16x8 __attribute__((ext_vector_type(8)));
typedef float f32x4  __attribute__((ext_vector_type(4)));

__device__ __forceinline__ unsigned int bf16rne(float f) {
  unsigned int x = __float_as_uint(f);
  return (x + 0x7fffu + ((x >> 16) & 1u)) >> 16;
}

// ---------------------------------------------------------------------------
// prep: bf16 transposed weights + fp32 effective bias. grid 1026 x 256.
//  blocks 0..255    : WphiT[n][c] = bf16(W_phi[c][n])   (128 x 512)
//  blocks 256..511  : W1T[j][p]   = bf16(W1[p][j])      (512 x 128)
//  blocks 512..1023 : W2T[n][k]   = bf16(W2[k][n])      (256 x 512)
//  blocks 1024..1025: b1eff[j]    = b1[j] + 512*(b_phi @ W1[:,j])  (fp32)
// ---------------------------------------------------------------------------
__global__ __launch_bounds__(256) void prep(
    const float* __restrict__ W_phi, const float* __restrict__ W1,
    const float* __restrict__ W2, const float* __restrict__ b_phi,
    const float* __restrict__ b1,
    unsigned short* __restrict__ WphiT, unsigned short* __restrict__ W1T,
    unsigned short* __restrict__ W2T, float* __restrict__ b1eff) {
  const int b = blockIdx.x, tid = threadIdx.x;
  if (b < 256) {
    int o = b * 256 + tid;
    int n = o >> 9, c = o & 511;
    WphiT[o] = (unsigned short)bf16rne(W_phi[c * PHI + n]);
  } else if (b < 512) {
    int o = (b - 256) * 256 + tid;
    int j = o >> 7, p = o & 127;
    W1T[o] = (unsigned short)bf16rne(W1[p * H1D + j]);
  } else if (b < 1024) {
    int o = (b - 512) * 256 + tid;
    int n = o >> 9, k = o & 511;
    W2T[o] = (unsigned short)bf16rne(W2[k * H2D + n]);
  } else {
    int j = (b - 1024) * 256 + tid;
    float a = 0.0f;
    #pragma unroll 8
    for (int p = 0; p < PHI; ++p) a += b_phi[p] * W1[p * H1D + j];
    b1eff[j] = b1[j] + 512.0f * a;
  }
}

// ---------------------------------------------------------------------------
// fused: per block of 16 batch rows (256 blocks, 512 threads = 8 waves):
//   hist (LDS atomics) -> u = Hist@WphiT^T -> h1 = relu(u@W1T^T + b1eff)
//   -> h2 = relu(h1@W2T^T + b2) -> out = h2@W3 + b3
// Hist/u/h1 live only in LDS. 8 waves split the column ranges (ph1: 16/wave,
// ph2: 64/wave, ph3: 32/wave) -> 2 waves/SIMD for latency hiding.
// MFMA 16x16x32: A-frag m=lane&15, k=(lane>>4)*8+i; C/D col=lane&15,
// row=(lane>>4)*4+reg.
// ---------------------------------------------------------------------------
__global__ __launch_bounds__(512) void fused(
    const int* __restrict__ x,
    const unsigned short* __restrict__ WphiT,
    const unsigned short* __restrict__ W1T,
    const unsigned short* __restrict__ W2T,
    const float* __restrict__ b1eff, const float* __restrict__ b2,
    const float* __restrict__ W3, const float* __restrict__ b3,
    float* __restrict__ out) {
  __shared__ unsigned int   hs[16 * 512];       // 32 KB
  __shared__ unsigned short hist_bf[16 * HS];   // 16.25 KB
  __shared__ unsigned short u_bf[16 * US];      // 4.25 KB
  __shared__ unsigned short h1_bf[16 * HS];     // 16.25 KB
  __shared__ float red[8][16];

  const int tid = threadIdx.x;
  const int w = tid >> 6, l = tid & 63;
  const int r = l & 15, q = l >> 4;
  const int bm = blockIdx.x * 16;

  // ---- phase 0: histogram of 16 rows (32 threads/row, 16 positions each) ----
  uint4* hs4 = (uint4*)hs;
  #pragma unroll
  for (int i = 0; i < 4; ++i) hs4[tid * 4 + i] = make_uint4(0, 0, 0, 0);
  __syncthreads();
  {
    const int row = tid >> 5, sub = tid & 31;
    const int* xp = x + (size_t)(bm + row) * N_POS + sub * 16;
    #pragma unroll
    for (int i = 0; i < 4; ++i) {
      int4 c = *(const int4*)(xp + i * 4);
      atomicAdd(&hs[row * 512 + c.x], 1u);
      atomicAdd(&hs[row * 512 + c.y], 1u);
      atomicAdd(&hs[row * 512 + c.z], 1u);
      atomicAdd(&hs[row * 512 + c.w], 1u);
    }
  }
  __syncthreads();
  {
    // counts <= 512 always -> bf16 exact
    const int row = tid >> 5, sub = tid & 31;
    const unsigned int* src = hs + row * 512 + sub * 16;
    unsigned short* dst = hist_bf + row * HS + sub * 16;
    #pragma unroll
    for (int i = 0; i < 2; ++i) {
      uint4 a = *(const uint4*)(src + i * 8);
      uint4 bq = *(const uint4*)(src + i * 8 + 4);
      uint4 o;
      o.x = bf16rne((float)a.x)  | (bf16rne((float)a.y)  << 16);
      o.y = bf16rne((float)a.z)  | (bf16rne((float)a.w)  << 16);
      o.z = bf16rne((float)bq.x) | (bf16rne((float)bq.y) << 16);
      o.w = bf16rne((float)bq.z) | (bf16rne((float)bq.w) << 16);
      *(uint4*)(dst + i * 8) = o;
    }
  }
  __syncthreads();

  // ---- phase 1: u = Hist @ WphiT^T  (K=512, N=128; wave w -> cols 16w..16w+15)
  f32x4 accu = (f32x4){0.f, 0.f, 0.f, 0.f};
  #pragma unroll 4
  for (int k0 = 0; k0 < N_CLS; k0 += 32) {
    bf16x8 af = *(const bf16x8*)&hist_bf[r * HS + k0 + q * 8];
    bf16x8 bfr = *(const bf16x8*)(WphiT + (size_t)(16 * w + r) * N_CLS + k0 + q * 8);
    accu = __builtin_amdgcn_mfma_f32_16x16x32_bf16(af, bfr, accu, 0, 0, 0);
  }
  #pragma unroll
  for (int reg = 0; reg < 4; ++reg)
    u_bf[(q * 4 + reg) * US + 16 * w + r] = (unsigned short)bf16rne(accu[reg]);
  __syncthreads();

  // ---- phase 2: h1 = relu(u @ W1T^T + b1eff)  (K=128, N=512; wave w -> cols 64w..)
  f32x4 acc1[4];
  #pragma unroll
  for (int j = 0; j < 4; ++j) acc1[j] = (f32x4){0.f, 0.f, 0.f, 0.f};
  #pragma unroll
  for (int k0 = 0; k0 < PHI; k0 += 32) {
    bf16x8 af = *(const bf16x8*)&u_bf[r * US + k0 + q * 8];
    #pragma unroll
    for (int tt = 0; tt < 4; ++tt) {
      bf16x8 bfr = *(const bf16x8*)(W1T + (size_t)(64 * w + 16 * tt + r) * PHI + k0 + q * 8);
      acc1[tt] = __builtin_amdgcn_mfma_f32_16x16x32_bf16(af, bfr, acc1[tt], 0, 0, 0);
    }
  }
  #pragma unroll
  for (int tt = 0; tt < 4; ++tt) {
    const int col = 64 * w + 16 * tt + r;
    const float bv = b1eff[col];
    #pragma unroll
    for (int reg = 0; reg < 4; ++reg) {
      float v = fmaxf(acc1[tt][reg] + bv, 0.0f);
      h1_bf[(q * 4 + reg) * HS + col] = (unsigned short)bf16rne(v);
    }
  }
  __syncthreads();

  // ---- phase 3: h2 = relu(h1 @ W2T^T + b2); out = h2 @ W3 + b3
  //      (K=512, N=256; wave w -> cols 32w..32w+31)
  f32x4 acc2[2];
  acc2[0] = (f32x4){0.f, 0.f, 0.f, 0.f};
  acc2[1] = (f32x4){0.f, 0.f, 0.f, 0.f};
  #pragma unroll 4
  for (int k0 = 0; k0 < H1D; k0 += 32) {
    bf16x8 af = *(const bf16x8*)&h1_bf[r * HS + k0 + q * 8];
    #pragma unroll
    for (int tt = 0; tt < 2; ++tt) {
      bf16x8 bfr = *(const bf16x8*)(W2T + (size_t)(32 * w + 16 * tt + r) * H1D + k0 + q * 8);
      acc2[tt] = __builtin_amdgcn_mfma_f32_16x16x32_bf16(af, bfr, acc2[tt], 0, 0, 0);
    }
  }
  float part[4] = {0.f, 0.f, 0.f, 0.f};
  #pragma unroll
  for (int tt = 0; tt < 2; ++tt) {
    const int col = 32 * w + 16 * tt + r;
    const float bv = b2[col];
    const float w3 = W3[col];
    #pragma unroll
    for (int reg = 0; reg < 4; ++reg)
      part[reg] += fmaxf(acc2[tt][reg] + bv, 0.0f) * w3;
  }
  #pragma unroll
  for (int off = 1; off < 16; off <<= 1)
    #pragma unroll
    for (int reg = 0; reg < 4; ++reg)
      part[reg] += __shfl_xor(part[reg], off, 64);
  if (r == 0)
    #pragma unroll
    for (int reg = 0; reg < 4; ++reg) red[w][q * 4 + reg] = part[reg];
  __syncthreads();
  if (tid < 16) {
    float s = b3[0];
    #pragma unroll
    for (int ww = 0; ww < 8; ++ww) s += red[ww][tid];
    out[bm + tid] = s;
  }
}

// ---------------------------------------------------------------------------
extern "C" void kernel_launch(void* const* d_in, const int* in_sizes, int n_in,
                              void* d_out, int out_size, void* d_ws, size_t ws_size,
                              hipStream_t stream) {
  const int*   x     = (const int*)  d_in[0];
  const float* W_phi = (const float*)d_in[1];
  const float* b_phi = (const float*)d_in[2];
  const float* W1    = (const float*)d_in[3];
  const float* b1    = (const float*)d_in[4];
  const float* W2    = (const float*)d_in[5];
  const float* b2    = (const float*)d_in[6];
  const float* W3    = (const float*)d_in[7];
  const float* b3    = (const float*)d_in[8];
  float* out = (float*)d_out;

  char* ws = (char*)d_ws;
  unsigned short* WphiT = (unsigned short*)(ws);            // 128 KB
  unsigned short* W1T   = (unsigned short*)(ws + 131072);   // 128 KB
  unsigned short* W2T   = (unsigned short*)(ws + 262144);   // 256 KB
  float*          b1eff = (float*)         (ws + 524288);   // 2 KB

  prep<<<1026, 256, 0, stream>>>(W_phi, W1, W2, b_phi, b1,
                                 WphiT, W1T, W2T, b1eff);
  fused<<<B_SZ / 16, 512, 0, stream>>>(x, WphiT, W1T, W2T,
                                       b1eff, b2, W3, b3, out);
}